// Round 3
// baseline (135.957 us; speedup 1.0000x reference)
//
#include <hip/hip_runtime.h>
#include <stdint.h>

// ---------------------------------------------------------------------------
// SelfAttentiveBimodalFusion: MLP(192->16->16) -> Q(8),K(8),V(64) -> full
// N x N attention -> out (N,64).  N = 12288.  fp32 in / fp32 out.
// Validated r5-r12: absmax 9.8e-4 vs thr 2.7e-3.
//
// Ladder: r5 killed atomics, r7 occupancy, r9 global_load_lds DMA -> k2=50us,
// r10 query-split waves + bf16 partials -> k2=46us (VALU 55%, Mfma 22%).
// r11 FAILED: launch_bounds(256,6) caps unified VGPR+AGPR at 85/wave ->
// scratch spill, 226 MB writes, k2=98us.  launch_bounds is a HARD promise.
// r12: same algebra at (256,4): k2=44us -- only -2us vs r10.  FALSIFIES
// "VALU-issue-bound": removing 25% of VALU work didn't move time.  k2 is
// latency/serialization-bound: 4-wave lockstep barrier every 64 keys and
// only 4 resident blocks/CU to overlap the bubbles.
// r13 (this): shrink the sync domain.  2-wave blocks (128 thr): barrier
// width /2, resident blocks/CU 4 -> 8 (LDS 8x18.4KB=147KB), epilogue 4 ->
// 2 serialized rounds.  V-tile L2 traffic 170 -> 340 MB (~10 TB/s, safe).
// Per-wave inner algebra byte-identical to r12.
// ---------------------------------------------------------------------------

#define NN 12288

typedef float    f32x16 __attribute__((ext_vector_type(16)));
typedef short    s16x8  __attribute__((ext_vector_type(8)));
typedef unsigned short u16;

#define MFMA_32x32x16_BF16 __builtin_amdgcn_mfma_f32_32x32x16_bf16

// ws layout (bytes)
#define OFF_QB   0u          // N*8*2   = 196608  (bf16, pre-scaled)
#define OFF_KB   196608u     // N*8*2   = 196608  (bf16)
#define OFF_VT   393216u     // 384 tiles * 4608 B = 1769472 (bf16 V, tiled)
#define OFF_PO   2162688u    // S*N*64*2 bf16 O partials; pl follows (S*N*4 fp32)

typedef __attribute__((address_space(3))) void lds_void_t;
typedef const __attribute__((address_space(1))) void gbl_void_t;
__device__ __forceinline__ void gld16(const void* g, void* l) {
    __builtin_amdgcn_global_load_lds((gbl_void_t*)g, (lds_void_t*)l, 16, 0, 0);
}

__device__ __forceinline__ float bf2f(u16 s) {
    union { unsigned int u; float f; } c; c.u = ((unsigned int)s) << 16; return c.f;
}
__device__ __forceinline__ u16 f2bf(float f) {
    union { float f; unsigned int u; } c; c.f = f;
    return (u16)((c.u + 0x8000u) >> 16);
}
__device__ __forceinline__ unsigned int pk2(float a, float b) {
    union { float f; unsigned int u; } ca, cb; ca.f = a; cb.f = b;
    return ((ca.u + 0x8000u) >> 16) | ((cb.u + 0x8000u) & 0xffff0000u);
}
// single-instruction packed f32->bf16 where available (gfx950), else manual
__device__ __forceinline__ unsigned int pkbf(float a, float b) {
#if __has_builtin(__builtin_amdgcn_cvt_pk_bf16_f32)
    auto r = __builtin_amdgcn_cvt_pk_bf16_f32(a, b);
    union { decltype(r) v; unsigned int u; } c; c.v = r; return c.u;
#else
    return pk2(a, b);
#endif
}
__device__ __forceinline__ f32x16 zf16() {
    f32x16 z;
#pragma unroll
    for (int i = 0; i < 16; ++i) z[i] = 0.f;
    return z;
}
__device__ __forceinline__ s16x8 zs8() {
    s16x8 z;
#pragma unroll
    for (int i = 0; i < 8; ++i) z[i] = 0;
    return z;
}

union U8 { s16x8 v; unsigned int u[4]; };

// ---------------- kernel 1: detect + weights->LDS + MLP -> Qb, Kb, Vt -------
// (r9-validated, unchanged)
__global__ __launch_bounds__(256) void k1_qkv(
    const void* __restrict__ xmain, const void* __restrict__ xmod,
    const void* __restrict__ we1, const void* __restrict__ we2,
    const void* __restrict__ wqp, const void* __restrict__ wkp,
    const void* __restrict__ wvp,
    u16* __restrict__ qb, u16* __restrict__ kb, u16* __restrict__ vt)
{
    __shared__ float wf[4608];
    __shared__ int   sflag;
    __shared__ float lh1[64][4][17];
    __shared__ float lh2[64][17];

    const int t = threadIdx.x;
    const int r = t >> 2;
    const int p = t & 3;
    const int row = blockIdx.x * 64 + r;

    if (t == 0) sflag = 0;
    __syncthreads();
    {
        float v = bf2f(((const u16*)xmod)[2 * t]);
        if (fabsf(v) > 16.f) atomicAdd(&sflag, 1);
    }
    __syncthreads();
    const int isf32 = (sflag > 8);

    const float SCL = 0.51006979f;       // (1/sqrt(8)) * log2(e)
    if (isf32) {
        const float* a1 = (const float*)we1; const float* a2 = (const float*)we2;
        const float* aq = (const float*)wqp; const float* ak = (const float*)wkp;
        const float* av = (const float*)wvp;
        for (int i = t; i < 4608; i += 256) {
            if      (i < 3072) wf[i] = a1[i];
            else if (i < 3328) wf[i] = a2[i - 3072];
            else if (i < 3456) wf[i] = aq[i - 3328] * SCL;
            else if (i < 3584) wf[i] = ak[i - 3456];
            else               wf[i] = av[i - 3584];
        }
    } else {
        const u16* a1 = (const u16*)we1; const u16* a2 = (const u16*)we2;
        const u16* aq = (const u16*)wqp; const u16* ak = (const u16*)wkp;
        const u16* av = (const u16*)wvp;
        for (int i = t; i < 4608; i += 256) {
            if      (i < 3072) wf[i] = bf2f(a1[i]);
            else if (i < 3328) wf[i] = bf2f(a2[i - 3072]);
            else if (i < 3456) wf[i] = bf2f(aq[i - 3328]) * SCL;
            else if (i < 3584) wf[i] = bf2f(ak[i - 3456]);
            else               wf[i] = bf2f(av[i - 3584]);
        }
    }
    __syncthreads();

    const float* __restrict__ W1 = wf;
    const float* __restrict__ W2 = wf + 3072;
    const float* __restrict__ Wq = wf + 3328;
    const float* __restrict__ Wk = wf + 3456;
    const float* __restrict__ Wv = wf + 3584;

    float h1p[16];
#pragma unroll
    for (int o = 0; o < 16; ++o) h1p[o] = 0.f;

    if (isf32) {
#pragma unroll
        for (int cc = 0; cc < 12; ++cc) {
            const int c = p + cc * 4;
            float4 xv = (c < 16)
                ? ((const float4*)xmain)[(size_t)row * 16 + c]
                : ((const float4*)xmod)[(size_t)row * 32 + (c - 16)];
            float xs[4] = {xv.x, xv.y, xv.z, xv.w};
#pragma unroll
            for (int j = 0; j < 4; ++j) {
                const float* wr = W1 + (c * 4 + j) * 16;
#pragma unroll
                for (int o = 0; o < 16; ++o) h1p[o] += xs[j] * wr[o];
            }
        }
    } else {
#pragma unroll
        for (int cc = 0; cc < 12; ++cc) {
            const int c = p + cc * 4;
            uint2 xv = (c < 16)
                ? ((const uint2*)xmain)[(size_t)row * 16 + c]
                : ((const uint2*)xmod)[(size_t)row * 32 + (c - 16)];
            float xs[4] = { bf2f((u16)(xv.x & 0xffff)), bf2f((u16)(xv.x >> 16)),
                            bf2f((u16)(xv.y & 0xffff)), bf2f((u16)(xv.y >> 16)) };
#pragma unroll
            for (int j = 0; j < 4; ++j) {
                const float* wr = W1 + (c * 4 + j) * 16;
#pragma unroll
                for (int o = 0; o < 16; ++o) h1p[o] += xs[j] * wr[o];
            }
        }
    }
#pragma unroll
    for (int o = 0; o < 16; ++o) lh1[r][p][o] = h1p[o];
    __syncthreads();

    float h1[16];
#pragma unroll
    for (int o = 0; o < 16; ++o)
        h1[o] = fmaxf(lh1[r][0][o] + lh1[r][1][o] + lh1[r][2][o] + lh1[r][3][o], 0.f);

#pragma unroll
    for (int oo = 0; oo < 4; ++oo) {
        const int o = p * 4 + oo;
        float s = 0.f;
#pragma unroll
        for (int j = 0; j < 16; ++j) s += h1[j] * W2[j * 16 + o];
        lh2[r][o] = fmaxf(s, 0.f);
    }
    __syncthreads();

    float h2[16];
#pragma unroll
    for (int j = 0; j < 16; ++j) h2[j] = lh2[r][j];

    {
        float q0 = 0.f, q1 = 0.f, k0 = 0.f, k1 = 0.f;
        const int o = 2 * p;
#pragma unroll
        for (int j = 0; j < 16; ++j) {
            q0 += h2[j] * Wq[j * 8 + o];
            q1 += h2[j] * Wq[j * 8 + o + 1];
            k0 += h2[j] * Wk[j * 8 + o];
            k1 += h2[j] * Wk[j * 8 + o + 1];
        }
        ((unsigned int*)qb)[(size_t)row * 4 + p] = pk2(q0, q1);
        ((unsigned int*)kb)[(size_t)row * 4 + p] = pk2(k0, k1);
    }

    // V store, key-tiled layout: [tile][c][kk], row stride 36 u16 (72 B)
    const int tI = row >> 5, kk = row & 31;
#pragma unroll
    for (int c16 = 0; c16 < 16; ++c16) {
        const int c = p * 16 + c16;
        float v = 0.f;
#pragma unroll
        for (int j = 0; j < 16; ++j) v += h2[j] * Wv[j * 64 + c];
        vt[(size_t)tI * 2304 + c * 36 + kk] = f2bf(v);
    }
}

// --------------------------- kernel 2: attention partials -------------------
// grid = 192 q-blocks * S key-splits; block = 128 threads = 2 waves x 32q;
// the wave PAIR shares one DMA-staged 64-key V-chunk double buffer (LDS
// 18432 B).  One 2-wave barrier per 64 keys; 8 resident blocks/CU overlap
// each other's DMA/barrier bubbles.  Softmax denominator via MFMA(ones, P).
// bf16 partials out, no atomics.
// Register budget (r11 lesson): launch_bounds(128,4) -> 128-reg/wave cap on
// the unified VGPR+AGPR file; acc0+acc1+accl = 48 AGPR + ~40 arch VGPR +
// one live S (16) + ka prefetch (16) ~= 112.  Do NOT tighten.

// one 32-key tile: exp -> pack -> l-sum MFMA -> 4 PV MFMAs (r5 relabeling)
__device__ __forceinline__ void tile_pv(
    const f32x16& S, const u16* __restrict__ base, int l31, int half,
    const s16x8& ones, f32x16& acc0, f32x16& acc1, f32x16& accl)
{
    float pr[16];
#pragma unroll
    for (int r = 0; r < 16; ++r) pr[r] = __builtin_amdgcn_exp2f(S[r]);

    U8 p0, p1;
#pragma unroll
    for (int i = 0; i < 4; ++i) {
        p0.u[i] = pkbf(pr[2 * i],     pr[2 * i + 1]);
        p1.u[i] = pkbf(pr[8 + 2 * i], pr[8 + 2 * i + 1]);
    }

    // denominator: every output row of MFMA(1, P) = sum_k P[k][q]; the MFMA
    // contracts over both lane-halves' k-slices, so no shfl_xor needed later.
    accl = MFMA_32x32x16_BF16(ones, p0.v, accl, 0, 0, 0);
    accl = MFMA_32x32x16_BF16(ones, p1.v, accl, 0, 0, 0);

    const u16* r0 = base + l31 * 36 + 4 * half;          // channels 0..31
    const u16* r1 = base + (32 + l31) * 36 + 4 * half;   // channels 32..63
    U8 va;
    uint2 x0, x1;
    x0 = *(const uint2*)(r0);       x1 = *(const uint2*)(r0 + 8);
    va.u[0] = x0.x; va.u[1] = x0.y; va.u[2] = x1.x; va.u[3] = x1.y;
    acc0 = MFMA_32x32x16_BF16(va.v, p0.v, acc0, 0, 0, 0);
    x0 = *(const uint2*)(r1);       x1 = *(const uint2*)(r1 + 8);
    va.u[0] = x0.x; va.u[1] = x0.y; va.u[2] = x1.x; va.u[3] = x1.y;
    acc1 = MFMA_32x32x16_BF16(va.v, p0.v, acc1, 0, 0, 0);
    x0 = *(const uint2*)(r0 + 16);  x1 = *(const uint2*)(r0 + 24);
    va.u[0] = x0.x; va.u[1] = x0.y; va.u[2] = x1.x; va.u[3] = x1.y;
    acc0 = MFMA_32x32x16_BF16(va.v, p1.v, acc0, 0, 0, 0);
    x0 = *(const uint2*)(r1 + 16);  x1 = *(const uint2*)(r1 + 24);
    va.u[0] = x0.x; va.u[1] = x0.y; va.u[2] = x1.x; va.u[3] = x1.y;
    acc1 = MFMA_32x32x16_BF16(va.v, p1.v, acc1, 0, 0, 0);
}

__global__ __launch_bounds__(128, 4) void k2_attn(
    const u16* __restrict__ qb, const u16* __restrict__ kb,
    const u16* __restrict__ vt,
    u16* __restrict__ po, float* __restrict__ pl,
    int nsplit, int niter)
{
    __shared__ union SM {
        uint4 stage[2][576];                 // 2 x 9216 B = 64-key V double buf
        float sf[2304];                      // epilogue transpose (aliased)
    } sm;

    const int tid  = threadIdx.x;
    const int lane = tid & 63;
    const int half = lane >> 5;
    const int l31  = lane & 31;
    const int w    = tid >> 6;               // wave 0..1
    const int qB   = (blockIdx.x % 192) * 64;
    const int sp   = blockIdx.x / 192;
    const int myq  = qB + 32 * w;            // this wave's first query
    const int key_start = sp * (NN / nsplit);
    const int c0 = key_start >> 6;           // 64-key chunk index

    const f32x16 Z = zf16();
    s16x8 qf = zs8();
    if (!half) qf = *(const s16x8*)(qb + (size_t)(myq + l31) * 8);

    s16x8 ones;
#pragma unroll
    for (int i = 0; i < 8; ++i) ones[i] = (short)0x3F80;   // bf16 1.0

    f32x16 acc0 = Z, acc1 = Z, accl = Z;

    // DMA chunk 0 -> stage[0]; wave w stages bytes [4608w, 4608w+4608)
    {
        const char* g = (const char*)vt + (size_t)c0 * 9216 + 4608 * w + lane * 16;
        char* l = (char*)&sm.stage[0][0] + 4608 * w;   // wave-uniform base
        gld16(g, l);
        gld16(g + 1024, l + 1024);
        gld16(g + 2048, l + 2048);
        gld16(g + 3072, l + 3072);
        if (lane < 32) gld16(g + 4096, l + 4096);
    }
    const s16x8* kp = (const s16x8*)kb;      // one s16x8 per key
    s16x8 ka_c0 = kp[key_start + l31];
    s16x8 ka_c1 = kp[key_start + 32 + l31];

    for (int it = 0; it < niter; ++it) {
        __builtin_amdgcn_s_waitcnt(0x0F70);  // vmcnt(0): my DMA + ka done
        __syncthreads();                     // pair's DMA visible; prev buf free
        const int cb = it & 1;
        const bool has_next = (it + 1 < niter);

        s16x8 ka_n0, ka_n1;
        if (has_next) {
            const int nk = key_start + (it + 1) * 64 + l31;
            ka_n0 = kp[nk];
            ka_n1 = kp[nk + 32];
            const char* g = (const char*)vt + (size_t)(c0 + it + 1) * 9216
                          + 4608 * w + lane * 16;
            char* l = (char*)&sm.stage[cb ^ 1][0] + 4608 * w;
            gld16(g, l);
            gld16(g + 1024, l + 1024);
            gld16(g + 2048, l + 2048);
            gld16(g + 3072, l + 3072);
            if (lane < 32) gld16(g + 4096, l + 4096);
        }

        const u16* baseA = (const u16*)&sm.stage[cb][0];

        // single-S-live: Sa -> tile A, then Sb -> tile B (r11 spilled because
        // both S tiles were held across tile A's PV phase)
        {
            f32x16 Sa = MFMA_32x32x16_BF16(ka_c0, qf, Z, 0, 0, 0);
            tile_pv(Sa, baseA, l31, half, ones, acc0, acc1, accl);
        }
        {
            f32x16 Sb = MFMA_32x32x16_BF16(ka_c1, qf, Z, 0, 0, 0);
            tile_pv(Sb, baseA + 2304, l31, half, ones, acc0, acc1, accl);
        }

        if (has_next) { ka_c0 = ka_n0; ka_c1 = ka_n1; }
    }

    // denominator: all accl rows identical = full 64-lane key-sum per query
    const float ls = accl[0];

    // ---- epilogue: per-wave transpose through the (aliased) staging LDS ----
    // 2 rounds (one per wave); each thread packs 16 channels of one query.
    u16* poS = po + (size_t)sp * (NN * 64);
    for (int j = 0; j < 2; ++j) {
        __syncthreads();
        if (w == j) {
#pragma unroll
            for (int r = 0; r < 16; ++r) {
                const int c = (r & 3) + 8 * (r >> 2) + 4 * half;
                sm.sf[c * 33 + l31]        = acc0[r];
                sm.sf[(32 + c) * 33 + l31] = acc1[r];
            }
            if (lane < 32) sm.sf[2112 + l31] = ls;
        }
        __syncthreads();
        const int rq = tid >> 2;             // query 0..31
        const int cb0 = (tid & 3) * 16;      // channel base (16 ch/thread)
        unsigned int u0 = pkbf(sm.sf[(cb0 + 0) * 33 + rq], sm.sf[(cb0 + 1) * 33 + rq]);
        unsigned int u1 = pkbf(sm.sf[(cb0 + 2) * 33 + rq], sm.sf[(cb0 + 3) * 33 + rq]);
        unsigned int u2 = pkbf(sm.sf[(cb0 + 4) * 33 + rq], sm.sf[(cb0 + 5) * 33 + rq]);
        unsigned int u3 = pkbf(sm.sf[(cb0 + 6) * 33 + rq], sm.sf[(cb0 + 7) * 33 + rq]);
        unsigned int u4 = pkbf(sm.sf[(cb0 + 8) * 33 + rq], sm.sf[(cb0 + 9) * 33 + rq]);
        unsigned int u5 = pkbf(sm.sf[(cb0 +10) * 33 + rq], sm.sf[(cb0 +11) * 33 + rq]);
        unsigned int u6 = pkbf(sm.sf[(cb0 +12) * 33 + rq], sm.sf[(cb0 +13) * 33 + rq]);
        unsigned int u7 = pkbf(sm.sf[(cb0 +14) * 33 + rq], sm.sf[(cb0 +15) * 33 + rq]);
        u16* dst = poS + (size_t)(qB + 32 * j + rq) * 64 + cb0;
        *(uint4*)(dst)     = make_uint4(u0, u1, u2, u3);
        *(uint4*)(dst + 8) = make_uint4(u4, u5, u6, u7);
        if (tid < 32)
            pl[(size_t)sp * NN + qB + 32 * j + tid] = sm.sf[2112 + tid];
    }
}

// --------------------------- kernel 3: reduce splits + normalize ------------
__global__ __launch_bounds__(256) void k3_norm(
    const u16* __restrict__ po, const float* __restrict__ pl,
    float4* __restrict__ out, int nsplit)
{
    const int i = blockIdx.x * 256 + threadIdx.x;   // 196608 float4 outputs
    const int row = i >> 4;
    const int c0 = (i & 15) * 4;
    float l = 0.f;
    float o0 = 0.f, o1 = 0.f, o2 = 0.f, o3 = 0.f;
    for (int s = 0; s < nsplit; ++s) {
        l += pl[(size_t)s * NN + row];
        uint2 p = *(const uint2*)(po + (size_t)s * (NN * 64) +
                                  (size_t)row * 64 + c0);
        o0 += bf2f((u16)(p.x & 0xffff)); o1 += bf2f((u16)(p.x >> 16));
        o2 += bf2f((u16)(p.y & 0xffff)); o3 += bf2f((u16)(p.y >> 16));
    }
    const float rl = 1.0f / l;
    out[i] = make_float4(o0 * rl, o1 * rl, o2 * rl, o3 * rl);
}

// ---------------------------------------------------------------------------
extern "C" void kernel_launch(void* const* d_in, const int* in_sizes, int n_in,
                              void* d_out, int out_size, void* d_ws, size_t ws_size,
                              hipStream_t stream)
{
    const void* xmain = d_in[0];
    const void* xmod  = d_in[1];
    // d_in[2] = xyz (unused by the reference)
    const void* we1   = d_in[3];
    const void* we2   = d_in[4];
    const void* wq    = d_in[5];
    const void* wk    = d_in[6];
    const void* wv    = d_in[7];

    char* ws = (char*)d_ws;
    u16*   qb   = (u16*)  (ws + OFF_QB);
    u16*   kb   = (u16*)  (ws + OFF_KB);
    u16*   vt   = (u16*)  (ws + OFF_VT);

    // pick the largest key-split S whose partials fit in ws
    int S = 1;
    for (int cand = 16; cand >= 1; cand >>= 1) {
        size_t need = (size_t)OFF_PO + (size_t)cand * (NN * 64 * 2) +
                      (size_t)cand * (NN * 4);
        if (ws_size >= need) { S = cand; break; }
    }
    u16*   po = (u16*)(ws + OFF_PO);
    float* pl = (float*)(ws + OFF_PO + (size_t)S * (NN * 64 * 2));
    const int niter = NN / (64 * S);

    k1_qkv<<<192, 256, 0, stream>>>(xmain, xmod, we1, we2, wq, wk, wv,
                                    qb, kb, vt);
    k2_attn<<<192 * S, 128, 0, stream>>>(qb, kb, vt, po, pl, S, niter);
    k3_norm<<<768, 256, 0, stream>>>(po, pl, (float4*)d_out, S);
}

// Round 4
// 129.959 us; speedup vs baseline: 1.0462x; 1.0462x over previous
//
#include <hip/hip_runtime.h>
#include <stdint.h>

// ---------------------------------------------------------------------------
// SelfAttentiveBimodalFusion: MLP(192->16->16) -> Q(8),K(8),V(64) -> full
// N x N attention -> out (N,64).  N = 12288.  fp32 in / fp32 out.
// Validated r5-r13: absmax 9.8e-4 vs thr 2.7e-3.
//
// Ladder: r5 killed atomics, r9 global_load_lds DMA -> k2=50us, r10 query-
// split waves + bf16 partials -> 46us, r12 MFMA-ones denominator + 64-key
// iters at (256,4) -> 44us.
// r11 FAILED: (256,6) caps unified VGPR+AGPR at 85/wave -> scratch spill.
// r13 FAILED: 128-thr blocks crossed the 128-reg occupancy bracket
// (52 VGPR + 48 AGPR + align > 128) -> 2 waves/SIMD, 47.5us.  Occupancy
// brackets count VGPR+AGPR TOTAL (waves halve at 64/128/256).
// Cross-round invariant: per-wave issue fraction ~20% at every barrier
// width -> waves stall ~870cy/iter on the per-iteration vmcnt(0) DRAIN
// (waits on the newest loads: next-chunk DMA + ka globals issued only one
// compute-phase earlier).
// r14 (this): drain-free counted-vmcnt pipeline (guide T3/T4):
//   (a) K fragments co-staged with V in one 10240B chunk (9216 V + 1024 K);
//       ka read from LDS -> vmem queue = exactly 3 DMA ops/chunk/wave.
//   (b) 4-stage LDS buffer, 2 chunks in flight: wait vmcnt(6) steady
//       (in-order retirement guarantees current chunk resident), raw
//       s_barrier + sched_barrier(0) fences, issue chunk i+3 post-barrier
//       into buf (i-1)&3.  Tail peeled at vmcnt(3)/vmcnt(0).
//   (c) LDS 40960B -> exactly 4 blocks/CU (= r12's 16 waves/CU residency).
// ---------------------------------------------------------------------------

#define NN 12288

typedef float    f32x16 __attribute__((ext_vector_type(16)));
typedef short    s16x8  __attribute__((ext_vector_type(8)));
typedef unsigned short u16;

#define MFMA_32x32x16_BF16 __builtin_amdgcn_mfma_f32_32x32x16_bf16

// ws layout (bytes)
#define OFF_QB   0u          // N*8*2 = 196608 (bf16 Q, pre-scaled)
#define OFF_VT   196608u     // 192 chunks * 10240 B = 1966080 (V 9216 + K 1024)
#define OFF_PO   2162688u    // S*N*64*2 bf16 O partials; pl follows (S*N*4 fp32)

// s_waitcnt imm: vm[3:0]=n, exp=7 (nowait), lgkm=0xF (nowait)
#define VMCNT(n) (0x0F70 | (n))

typedef __attribute__((address_space(3))) void lds_void_t;
typedef const __attribute__((address_space(1))) void gbl_void_t;
__device__ __forceinline__ void gld16(const void* g, void* l) {
    __builtin_amdgcn_global_load_lds((gbl_void_t*)g, (lds_void_t*)l, 16, 0, 0);
}

__device__ __forceinline__ float bf2f(u16 s) {
    union { unsigned int u; float f; } c; c.u = ((unsigned int)s) << 16; return c.f;
}
__device__ __forceinline__ u16 f2bf(float f) {
    union { float f; unsigned int u; } c; c.f = f;
    return (u16)((c.u + 0x8000u) >> 16);
}
__device__ __forceinline__ unsigned int pk2(float a, float b) {
    union { float f; unsigned int u; } ca, cb; ca.f = a; cb.f = b;
    return ((ca.u + 0x8000u) >> 16) | ((cb.u + 0x8000u) & 0xffff0000u);
}
__device__ __forceinline__ unsigned int pkbf(float a, float b) {
#if __has_builtin(__builtin_amdgcn_cvt_pk_bf16_f32)
    auto r = __builtin_amdgcn_cvt_pk_bf16_f32(a, b);
    union { decltype(r) v; unsigned int u; } c; c.v = r; return c.u;
#else
    return pk2(a, b);
#endif
}
__device__ __forceinline__ f32x16 zf16() {
    f32x16 z;
#pragma unroll
    for (int i = 0; i < 16; ++i) z[i] = 0.f;
    return z;
}
__device__ __forceinline__ s16x8 zs8() {
    s16x8 z;
#pragma unroll
    for (int i = 0; i < 8; ++i) z[i] = 0;
    return z;
}

union U8 { s16x8 v; unsigned int u[4]; };

// ---------------- kernel 1: detect + weights->LDS + MLP -> Qb, Vt(+K) ------
__global__ __launch_bounds__(256) void k1_qkv(
    const void* __restrict__ xmain, const void* __restrict__ xmod,
    const void* __restrict__ we1, const void* __restrict__ we2,
    const void* __restrict__ wqp, const void* __restrict__ wkp,
    const void* __restrict__ wvp,
    u16* __restrict__ qb, u16* __restrict__ vt)
{
    __shared__ float wf[4608];
    __shared__ int   sflag;
    __shared__ float lh1[64][4][17];
    __shared__ float lh2[64][17];

    const int t = threadIdx.x;
    const int r = t >> 2;
    const int p = t & 3;
    const int row = blockIdx.x * 64 + r;

    if (t == 0) sflag = 0;
    __syncthreads();
    {
        float v = bf2f(((const u16*)xmod)[2 * t]);
        if (fabsf(v) > 16.f) atomicAdd(&sflag, 1);
    }
    __syncthreads();
    const int isf32 = (sflag > 8);

    const float SCL = 0.51006979f;       // (1/sqrt(8)) * log2(e)
    if (isf32) {
        const float* a1 = (const float*)we1; const float* a2 = (const float*)we2;
        const float* aq = (const float*)wqp; const float* ak = (const float*)wkp;
        const float* av = (const float*)wvp;
        for (int i = t; i < 4608; i += 256) {
            if      (i < 3072) wf[i] = a1[i];
            else if (i < 3328) wf[i] = a2[i - 3072];
            else if (i < 3456) wf[i] = aq[i - 3328] * SCL;
            else if (i < 3584) wf[i] = ak[i - 3456];
            else               wf[i] = av[i - 3584];
        }
    } else {
        const u16* a1 = (const u16*)we1; const u16* a2 = (const u16*)we2;
        const u16* aq = (const u16*)wqp; const u16* ak = (const u16*)wkp;
        const u16* av = (const u16*)wvp;
        for (int i = t; i < 4608; i += 256) {
            if      (i < 3072) wf[i] = bf2f(a1[i]);
            else if (i < 3328) wf[i] = bf2f(a2[i - 3072]);
            else if (i < 3456) wf[i] = bf2f(aq[i - 3328]) * SCL;
            else if (i < 3584) wf[i] = bf2f(ak[i - 3456]);
            else               wf[i] = bf2f(av[i - 3584]);
        }
    }
    __syncthreads();

    const float* __restrict__ W1 = wf;
    const float* __restrict__ W2 = wf + 3072;
    const float* __restrict__ Wq = wf + 3328;
    const float* __restrict__ Wk = wf + 3456;
    const float* __restrict__ Wv = wf + 3584;

    float h1p[16];
#pragma unroll
    for (int o = 0; o < 16; ++o) h1p[o] = 0.f;

    if (isf32) {
#pragma unroll
        for (int cc = 0; cc < 12; ++cc) {
            const int c = p + cc * 4;
            float4 xv = (c < 16)
                ? ((const float4*)xmain)[(size_t)row * 16 + c]
                : ((const float4*)xmod)[(size_t)row * 32 + (c - 16)];
            float xs[4] = {xv.x, xv.y, xv.z, xv.w};
#pragma unroll
            for (int j = 0; j < 4; ++j) {
                const float* wr = W1 + (c * 4 + j) * 16;
#pragma unroll
                for (int o = 0; o < 16; ++o) h1p[o] += xs[j] * wr[o];
            }
        }
    } else {
#pragma unroll
        for (int cc = 0; cc < 12; ++cc) {
            const int c = p + cc * 4;
            uint2 xv = (c < 16)
                ? ((const uint2*)xmain)[(size_t)row * 16 + c]
                : ((const uint2*)xmod)[(size_t)row * 32 + (c - 16)];
            float xs[4] = { bf2f((u16)(xv.x & 0xffff)), bf2f((u16)(xv.x >> 16)),
                            bf2f((u16)(xv.y & 0xffff)), bf2f((u16)(xv.y >> 16)) };
#pragma unroll
            for (int j = 0; j < 4; ++j) {
                const float* wr = W1 + (c * 4 + j) * 16;
#pragma unroll
                for (int o = 0; o < 16; ++o) h1p[o] += xs[j] * wr[o];
            }
        }
    }
#pragma unroll
    for (int o = 0; o < 16; ++o) lh1[r][p][o] = h1p[o];
    __syncthreads();

    float h1[16];
#pragma unroll
    for (int o = 0; o < 16; ++o)
        h1[o] = fmaxf(lh1[r][0][o] + lh1[r][1][o] + lh1[r][2][o] + lh1[r][3][o], 0.f);

#pragma unroll
    for (int oo = 0; oo < 4; ++oo) {
        const int o = p * 4 + oo;
        float s = 0.f;
#pragma unroll
        for (int j = 0; j < 16; ++j) s += h1[j] * W2[j * 16 + o];
        lh2[r][o] = fmaxf(s, 0.f);
    }
    __syncthreads();

    float h2[16];
#pragma unroll
    for (int j = 0; j < 16; ++j) h2[j] = lh2[r][j];

    {
        float q0 = 0.f, q1 = 0.f, k0 = 0.f, k1 = 0.f;
        const int o = 2 * p;
#pragma unroll
        for (int j = 0; j < 16; ++j) {
            q0 += h2[j] * Wq[j * 8 + o];
            q1 += h2[j] * Wq[j * 8 + o + 1];
            k0 += h2[j] * Wk[j * 8 + o];
            k1 += h2[j] * Wk[j * 8 + o + 1];
        }
        ((unsigned int*)qb)[(size_t)row * 4 + p] = pk2(q0, q1);
        // K fragment into the chunk's K region (u32 units):
        // chunk = row>>6 (2560 u32 each), K base 2304, key row&63, word p
        ((unsigned int*)vt)[(size_t)(row >> 6) * 2560 + 2304 +
                            (row & 63) * 4 + p] = pk2(k0, k1);
    }

    // V store, chunk layout: [chunk][tile(2)][c][kk], row stride 36 u16 (72 B)
    const int ch = row >> 6, tI = (row >> 5) & 1, kk = row & 31;
#pragma unroll
    for (int c16 = 0; c16 < 16; ++c16) {
        const int c = p * 16 + c16;
        float v = 0.f;
#pragma unroll
        for (int j = 0; j < 16; ++j) v += h2[j] * Wv[j * 64 + c];
        vt[(size_t)ch * 5120 + tI * 2304 + c * 36 + kk] = f2bf(v);
    }
}

// --------------------------- kernel 2: attention partials -------------------
// grid = 96 q-blocks * S key-splits; block = 256 thr = 4 waves x 32q.
// 64-key chunks (V 9216B + K 1024B) in a 4-stage LDS pipeline, 2 chunks in
// flight, counted vmcnt (never 0 in steady state), raw s_barrier.
// Register budget (r11/r13 lessons): VGPR+AGPR total must stay <= 128 for
// 4 waves/SIMD; acc0+acc1+accl = 48 AGPR + ~45 arch VGPR ~= 96.

__device__ __forceinline__ void tile_pv(
    const f32x16& S, const u16* __restrict__ base, int l31, int half,
    const s16x8& ones, f32x16& acc0, f32x16& acc1, f32x16& accl)
{
    float pr[16];
#pragma unroll
    for (int r = 0; r < 16; ++r) pr[r] = __builtin_amdgcn_exp2f(S[r]);

    U8 p0, p1;
#pragma unroll
    for (int i = 0; i < 4; ++i) {
        p0.u[i] = pkbf(pr[2 * i],     pr[2 * i + 1]);
        p1.u[i] = pkbf(pr[8 + 2 * i], pr[8 + 2 * i + 1]);
    }

    // denominator: every output row of MFMA(1, P) = sum_k P[k][q]
    accl = MFMA_32x32x16_BF16(ones, p0.v, accl, 0, 0, 0);
    accl = MFMA_32x32x16_BF16(ones, p1.v, accl, 0, 0, 0);

    const u16* r0 = base + l31 * 36 + 4 * half;          // channels 0..31
    const u16* r1 = base + (32 + l31) * 36 + 4 * half;   // channels 32..63
    U8 va;
    uint2 x0, x1;
    x0 = *(const uint2*)(r0);       x1 = *(const uint2*)(r0 + 8);
    va.u[0] = x0.x; va.u[1] = x0.y; va.u[2] = x1.x; va.u[3] = x1.y;
    acc0 = MFMA_32x32x16_BF16(va.v, p0.v, acc0, 0, 0, 0);
    x0 = *(const uint2*)(r1);       x1 = *(const uint2*)(r1 + 8);
    va.u[0] = x0.x; va.u[1] = x0.y; va.u[2] = x1.x; va.u[3] = x1.y;
    acc1 = MFMA_32x32x16_BF16(va.v, p0.v, acc1, 0, 0, 0);
    x0 = *(const uint2*)(r0 + 16);  x1 = *(const uint2*)(r0 + 24);
    va.u[0] = x0.x; va.u[1] = x0.y; va.u[2] = x1.x; va.u[3] = x1.y;
    acc0 = MFMA_32x32x16_BF16(va.v, p1.v, acc0, 0, 0, 0);
    x0 = *(const uint2*)(r1 + 16);  x1 = *(const uint2*)(r1 + 24);
    va.u[0] = x0.x; va.u[1] = x0.y; va.u[2] = x1.x; va.u[3] = x1.y;
    acc1 = MFMA_32x32x16_BF16(va.v, p1.v, acc1, 0, 0, 0);
}

// one 64-key chunk: ka from LDS, 2x (QK MFMA -> tile_pv)
__device__ __forceinline__ void chunk_body(
    const u16* __restrict__ base, const s16x8& qf, const s16x8& ones,
    int l31, int half, f32x16& acc0, f32x16& acc1, f32x16& accl)
{
    const f32x16 Z = zf16();
    s16x8 ka0 = *(const s16x8*)(base + 4608 + l31 * 8);   // keys 0..31
    s16x8 ka1 = *(const s16x8*)(base + 4864 + l31 * 8);   // keys 32..63
    {
        f32x16 Sa = MFMA_32x32x16_BF16(ka0, qf, Z, 0, 0, 0);
        tile_pv(Sa, base, l31, half, ones, acc0, acc1, accl);
    }
    {
        f32x16 Sb = MFMA_32x32x16_BF16(ka1, qf, Z, 0, 0, 0);
        tile_pv(Sb, base + 2304, l31, half, ones, acc0, acc1, accl);
    }
}

__global__ __launch_bounds__(256, 4) void k2_attn(
    const u16* __restrict__ qb, const u16* __restrict__ vt,
    u16* __restrict__ po, float* __restrict__ pl,
    int nsplit, int niter)
{
    __shared__ union SM {
        uint4 stage[4][640];                 // 4 x 10240 B chunk pipeline
        float sf[2304];                      // epilogue transpose (aliased)
    } sm;

    const int tid  = threadIdx.x;
    const int lane = tid & 63;
    const int half = lane >> 5;
    const int l31  = lane & 31;
    const int w    = tid >> 6;               // wave 0..3
    const int qB   = (blockIdx.x % 96) * 128;
    const int sp   = blockIdx.x / 96;
    const int myq  = qB + 32 * w;            // this wave's first query
    const int key_start = sp * (NN / nsplit);
    const int ch0 = key_start >> 6;          // first 64-key chunk index

    const f32x16 Z = zf16();
    s16x8 qf = zs8();
    if (!half) qf = *(const s16x8*)(qb + (size_t)(myq + l31) * 8);

    s16x8 ones;
#pragma unroll
    for (int i = 0; i < 8; ++i) ones[i] = (short)0x3F80;   // bf16 1.0

    f32x16 acc0 = Z, acc1 = Z, accl = Z;

    // stage chunk c into buffer b: wave w covers bytes [2560w, 2560w+2560)
    // = exactly 3 vmem instructions per wave per chunk (vmcnt arithmetic).
    auto STAGE = [&](int c, int b) {
        const char* g = (const char*)vt + (size_t)(ch0 + c) * 10240
                      + 2560 * w + lane * 16;
        char* l = (char*)&sm.stage[b][0] + 2560 * w;   // wave-uniform base
        gld16(g, l);
        gld16(g + 1024, l + 1024);
        if (lane < 32) gld16(g + 2048, l + 2048);
    };

    // prologue: 3 chunks in flight (niter >= 12 always: S <= 16)
    STAGE(0, 0);
    STAGE(1, 1);
    STAGE(2, 2);

    // main loop: steady-state wait vmcnt(6) = chunks i+1, i+2 in flight;
    // in-order retirement => chunk i fully resident.  Raw barrier (no drain).
    int it = 0;
    for (; it + 2 < niter; ++it) {
        __builtin_amdgcn_sched_barrier(0);
        __builtin_amdgcn_s_waitcnt(VMCNT(6));
        __builtin_amdgcn_s_barrier();
        __builtin_amdgcn_sched_barrier(0);
        if (it + 3 < niter) STAGE(it + 3, (it + 3) & 3);  // buf (it-1)&3, free
        chunk_body((const u16*)&sm.stage[it & 3][0], qf, ones,
                   l31, half, acc0, acc1, accl);
    }
    // tail: it = niter-2 (one chunk in flight), then it = niter-1 (none)
    __builtin_amdgcn_sched_barrier(0);
    __builtin_amdgcn_s_waitcnt(VMCNT(3));
    __builtin_amdgcn_s_barrier();
    __builtin_amdgcn_sched_barrier(0);
    chunk_body((const u16*)&sm.stage[it & 3][0], qf, ones,
               l31, half, acc0, acc1, accl);
    ++it;
    __builtin_amdgcn_sched_barrier(0);
    __builtin_amdgcn_s_waitcnt(VMCNT(0));
    __builtin_amdgcn_s_barrier();
    __builtin_amdgcn_sched_barrier(0);
    chunk_body((const u16*)&sm.stage[it & 3][0], qf, ones,
               l31, half, acc0, acc1, accl);

    // denominator: all accl rows identical = full 64-lane key-sum per query
    const float ls = accl[0];

    // ---- epilogue: per-wave transpose through the (aliased) staging LDS ----
    u16* poS = po + (size_t)sp * (NN * 64);
    for (int j = 0; j < 4; ++j) {
        __syncthreads();
        if (w == j) {
#pragma unroll
            for (int r = 0; r < 16; ++r) {
                const int c = (r & 3) + 8 * (r >> 2) + 4 * half;
                sm.sf[c * 33 + l31]        = acc0[r];
                sm.sf[(32 + c) * 33 + l31] = acc1[r];
            }
            if (lane < 32) sm.sf[2112 + l31] = ls;
        }
        __syncthreads();
        const int rq = tid >> 3;             // query 0..31
        const int c0b = (tid & 7) * 8;       // channel base
        unsigned int u0 = pkbf(sm.sf[(c0b + 0) * 33 + rq], sm.sf[(c0b + 1) * 33 + rq]);
        unsigned int u1 = pkbf(sm.sf[(c0b + 2) * 33 + rq], sm.sf[(c0b + 3) * 33 + rq]);
        unsigned int u2 = pkbf(sm.sf[(c0b + 4) * 33 + rq], sm.sf[(c0b + 5) * 33 + rq]);
        unsigned int u3 = pkbf(sm.sf[(c0b + 6) * 33 + rq], sm.sf[(c0b + 7) * 33 + rq]);
        *(uint4*)(poS + (size_t)(qB + 32 * j + rq) * 64 + c0b) =
            make_uint4(u0, u1, u2, u3);
        if (tid < 32)
            pl[(size_t)sp * NN + qB + 32 * j + tid] = sm.sf[2112 + tid];
    }
}

// --------------------------- kernel 3: reduce splits + normalize ------------
__global__ __launch_bounds__(256) void k3_norm(
    const u16* __restrict__ po, const float* __restrict__ pl,
    float4* __restrict__ out, int nsplit)
{
    const int i = blockIdx.x * 256 + threadIdx.x;   // 196608 float4 outputs
    const int row = i >> 4;
    const int c0 = (i & 15) * 4;
    float l = 0.f;
    float o0 = 0.f, o1 = 0.f, o2 = 0.f, o3 = 0.f;
    for (int s = 0; s < nsplit; ++s) {
        l += pl[(size_t)s * NN + row];
        uint2 p = *(const uint2*)(po + (size_t)s * (NN * 64) +
                                  (size_t)row * 64 + c0);
        o0 += bf2f((u16)(p.x & 0xffff)); o1 += bf2f((u16)(p.x >> 16));
        o2 += bf2f((u16)(p.y & 0xffff)); o3 += bf2f((u16)(p.y >> 16));
    }
    const float rl = 1.0f / l;
    out[i] = make_float4(o0 * rl, o1 * rl, o2 * rl, o3 * rl);
}

// ---------------------------------------------------------------------------
extern "C" void kernel_launch(void* const* d_in, const int* in_sizes, int n_in,
                              void* d_out, int out_size, void* d_ws, size_t ws_size,
                              hipStream_t stream)
{
    const void* xmain = d_in[0];
    const void* xmod  = d_in[1];
    // d_in[2] = xyz (unused by the reference)
    const void* we1   = d_in[3];
    const void* we2   = d_in[4];
    const void* wq    = d_in[5];
    const void* wk    = d_in[6];
    const void* wv    = d_in[7];

    char* ws = (char*)d_ws;
    u16*   qb   = (u16*)  (ws + OFF_QB);
    u16*   vt   = (u16*)  (ws + OFF_VT);

    // pick the largest key-split S whose partials fit in ws
    int S = 1;
    for (int cand = 16; cand >= 1; cand >>= 1) {
        size_t need = (size_t)OFF_PO + (size_t)cand * (NN * 64 * 2) +
                      (size_t)cand * (NN * 4);
        if (ws_size >= need) { S = cand; break; }
    }
    u16*   po = (u16*)(ws + OFF_PO);
    float* pl = (float*)(ws + OFF_PO + (size_t)S * (NN * 64 * 2));
    const int niter = NN / (64 * S);

    k1_qkv<<<192, 256, 0, stream>>>(xmain, xmod, we1, we2, wq, wk, wv,
                                    qb, vt);
    k2_attn<<<96 * S, 256, 0, stream>>>(qb, vt, po, pl, S, niter);
    k3_norm<<<768, 256, 0, stream>>>(po, pl, (float4*)d_out, S);
}